// Round 5
// baseline (140.241 us; speedup 1.0000x reference)
//
#include <hip/hip_runtime.h>
#include <math.h>

#define EC 32
#define BLOCK 256

typedef float fvec4 __attribute__((ext_vector_type(4)));

__global__ __launch_bounds__(BLOCK) void ldif_fused_kernel(
    const float* __restrict__ pts,
    const fvec4* __restrict__ act,      // (EC, N) of float4
    const float* __restrict__ dists,
    const float* __restrict__ constants,
    const float* __restrict__ centers,
    const float* __restrict__ radii,
    const float* __restrict__ rotations,
    fvec4* __restrict__ out,
    float* __restrict__ penout,         // &out_flat[4*n]
    float* __restrict__ partials,
    unsigned int* __restrict__ counter,
    int n, int nblocks) {
    // params per component e (3 x float4), computed redundantly per-block:
    //  p0 = (cx, cy, cz, log2|c|)
    //  p1 = (Axx, Ayy, Azz, Axy)   A = -0.5*log2(e)*inv_cov, off-diag doubled
    //  p2 = (Axz, Ayz, 0, 0)
    __shared__ float4 sp[EC * 3];
    __shared__ float sred[4];
    __shared__ double rd[BLOCK];
    __shared__ int sdone;

    const int tid = threadIdx.x;
    if (tid < EC) {
        int e = tid;
        float r = fabsf(radii[e]);
        float dinv = 1.0f / (r + 1e-8f);
        float rx = rotations[3 * e + 0], ry = rotations[3 * e + 1], rz = rotations[3 * e + 2];
        float cx = cosf(rx), cy = cosf(ry), cz = cosf(rz);
        float sx = sinf(rx), sy = sinf(ry), sz = sinf(rz);
        float R00 = cz * cy, R01 = cz * sy * sx - sz * cx, R02 = cz * sy * cx + sz * sx;
        float R10 = sz * cy, R11 = sz * sy * sx + cz * cx, R12 = sz * sy * cx - cz * sx;
        float R20 = -sy,     R21 = cy * sx,                R22 = cy * cx;
        float ic00 = dinv * (R00 * R00 + R01 * R01 + R02 * R02);
        float ic11 = dinv * (R10 * R10 + R11 * R11 + R12 * R12);
        float ic22 = dinv * (R20 * R20 + R21 * R21 + R22 * R22);
        float ic01 = dinv * (R00 * R10 + R01 * R11 + R02 * R12);
        float ic02 = dinv * (R00 * R20 + R01 * R21 + R02 * R22);
        float ic12 = dinv * (R10 * R20 + R11 * R21 + R12 * R22);
        const float NH = -0.72134752044f;  // -0.5 * log2(e)
        float lc = log2f(fabsf(constants[e]));
        sp[3 * e + 0] = make_float4(centers[3 * e + 0], centers[3 * e + 1], centers[3 * e + 2], lc);
        sp[3 * e + 1] = make_float4(NH * ic00, NH * ic11, NH * ic22, 2.0f * NH * ic01);
        sp[3 * e + 2] = make_float4(2.0f * NH * ic02, 2.0f * NH * ic12, 0.0f, 0.0f);
    }
    __syncthreads();

    long long i = (long long)blockIdx.x * BLOCK + tid;
    float pen = 0.0f;
    if (i < n) {
        const float LOG2E = 1.44269504f;
        float px = pts[3 * i + 0];
        float py = pts[3 * i + 1];
        float pz = pts[3 * i + 2];
        float dl = dists[i] * LOG2E;

        float s = 0.0f;
        float a0 = 0.0f, a1 = 0.0f, a2 = 0.0f, a3 = 0.0f;
#pragma unroll 8
        for (int e = 0; e < EC; ++e) {
            fvec4 a = __builtin_nontemporal_load(&act[(size_t)e * (size_t)n + (size_t)i]);
            float4 c0 = sp[3 * e + 0];
            float4 c1 = sp[3 * e + 1];
            float4 c2 = sp[3 * e + 2];
            float dx = px - c0.x, dy = py - c0.y, dz = pz - c0.z;
            float q = (c1.x * dx + c1.w * dy + c2.x * dz) * dx
                    + (c1.y * dy + c2.y * dz) * dy
                    + (c1.z * dz) * dz + c0.w;
            float v = __builtin_amdgcn_exp2f(q);  // = |c| * exp(-0.5 diff^T invcov diff)
            s += v;
            pen += fabsf(v - 0.005f);
            float s0 = __builtin_amdgcn_rcpf(1.0f + __builtin_amdgcn_exp2f(-LOG2E * a.x));
            float s1 = __builtin_amdgcn_rcpf(1.0f + __builtin_amdgcn_exp2f(-LOG2E * a.y));
            float s2 = __builtin_amdgcn_rcpf(1.0f + __builtin_amdgcn_exp2f(-LOG2E * a.z));
            float al = 1.0f - __builtin_amdgcn_exp2f(-fmaxf(a.w, 0.0f) * dl);
            a0 += v * s0;
            a1 += v * s1;
            a2 += v * s2;
            a3 += v * al;
        }
        float rn = __builtin_amdgcn_rcpf(s + 0.01f);
        fvec4 o;
        o.x = a0 * rn; o.y = a1 * rn; o.z = a2 * rn; o.w = a3 * rn;
        __builtin_nontemporal_store(o, &out[i]);
    }

    // deterministic per-block reduction: wave butterfly then fixed-order LDS combine
    float w = pen;
#pragma unroll
    for (int off = 32; off >= 1; off >>= 1) w += __shfl_xor(w, off);
    if ((tid & 63) == 0) sred[tid >> 6] = w;
    __syncthreads();
    if (tid == 0) {
        float bp = ((sred[0] + sred[1]) + sred[2]) + sred[3];
        partials[blockIdx.x] = bp;
        __threadfence();  // release: make partial visible device-wide
        unsigned int old = atomicAdd(counter, 1u);
        sdone = (old == (unsigned int)(nblocks - 1)) ? 1 : 0;
    }
    __syncthreads();

    if (sdone) {
        __threadfence();  // acquire: see all partials
        const volatile float* vp = partials;
        double s = 0.0;
        for (int j = tid; j < nblocks; j += BLOCK) s += (double)vp[j];
        rd[tid] = s;
        __syncthreads();
        for (int st = BLOCK / 2; st > 0; st >>= 1) {
            if (tid < st) rd[tid] += rd[tid + st];
            __syncthreads();
        }
        if (tid == 0) *penout = (float)(rd[0] / (double)n);
    }
}

extern "C" void kernel_launch(void* const* d_in, const int* in_sizes, int n_in,
                              void* d_out, int out_size, void* d_ws, size_t ws_size,
                              hipStream_t stream) {
    const float* pts       = (const float*)d_in[0];  // (N,3)
    const float* act       = (const float*)d_in[1];  // (EC,N,4)
    const float* dists     = (const float*)d_in[2];  // (N,1)
    const float* constants = (const float*)d_in[3];  // (EC,1)
    const float* centers   = (const float*)d_in[4];  // (EC,3)
    const float* radii     = (const float*)d_in[5];  // (EC,1)
    const float* rotations = (const float*)d_in[6];  // (EC,3)
    float* out = (float*)d_out;

    int n = in_sizes[0] / 3;
    unsigned int* counter = (unsigned int*)d_ws;
    float* partials = (float*)((char*)d_ws + 256);

    int nblocks = (n + BLOCK - 1) / BLOCK;

    hipMemsetAsync(d_ws, 0, sizeof(unsigned int), stream);
    ldif_fused_kernel<<<nblocks, BLOCK, 0, stream>>>(
        pts, (const fvec4*)act, dists, constants, centers, radii, rotations,
        (fvec4*)out, out + (size_t)4 * n, partials, counter, n, nblocks);
}

// Round 6
// 65.916 us; speedup vs baseline: 2.1276x; 2.1276x over previous
//
#include <hip/hip_runtime.h>
#include <math.h>

#define EC 32
#define BLOCK 256

typedef float fvec4 __attribute__((ext_vector_type(4)));

// Penalty accumulator: one u64. Bits [0,52) = fixed-point sum (scale 2^22),
// bits [52,64) = completed-block count. Integer adds commute exactly ->
// deterministic result independent of block order; the block whose returned
// count == nblocks-1 holds the exact final total (old + own) with no fence.
#define PEN_SCALE 4194304.0   // 2^22
#define CNT_SHIFT 52

__global__ __launch_bounds__(BLOCK) void ldif_fused_kernel(
    const float* __restrict__ pts,
    const fvec4* __restrict__ act,      // (EC, N) of float4
    const float* __restrict__ dists,
    const float* __restrict__ constants,
    const float* __restrict__ centers,
    const float* __restrict__ radii,
    const float* __restrict__ rotations,
    fvec4* __restrict__ out,
    float* __restrict__ penout,         // &out_flat[4*n]
    unsigned long long* __restrict__ pen_acc,
    int n, int nblocks) {
    // params per component e (3 x float4), computed redundantly per-block:
    //  p0 = (cx, cy, cz, log2|c|)
    //  p1 = (Axx, Ayy, Azz, Axy)   A = -0.5*log2(e)*inv_cov, off-diag doubled
    //  p2 = (Axz, Ayz, 0, 0)
    __shared__ float4 sp[EC * 3];
    __shared__ float sred[4];

    const int tid = threadIdx.x;
    if (tid < EC) {
        int e = tid;
        float r = fabsf(radii[e]);
        float dinv = 1.0f / (r + 1e-8f);
        float rx = rotations[3 * e + 0], ry = rotations[3 * e + 1], rz = rotations[3 * e + 2];
        float cx = cosf(rx), cy = cosf(ry), cz = cosf(rz);
        float sx = sinf(rx), sy = sinf(ry), sz = sinf(rz);
        float R00 = cz * cy, R01 = cz * sy * sx - sz * cx, R02 = cz * sy * cx + sz * sx;
        float R10 = sz * cy, R11 = sz * sy * sx + cz * cx, R12 = sz * sy * cx - cz * sx;
        float R20 = -sy,     R21 = cy * sx,                R22 = cy * cx;
        float ic00 = dinv * (R00 * R00 + R01 * R01 + R02 * R02);
        float ic11 = dinv * (R10 * R10 + R11 * R11 + R12 * R12);
        float ic22 = dinv * (R20 * R20 + R21 * R21 + R22 * R22);
        float ic01 = dinv * (R00 * R10 + R01 * R11 + R02 * R12);
        float ic02 = dinv * (R00 * R20 + R01 * R21 + R02 * R22);
        float ic12 = dinv * (R10 * R20 + R11 * R21 + R12 * R22);
        const float NH = -0.72134752044f;  // -0.5 * log2(e)
        float lc = log2f(fabsf(constants[e]));
        sp[3 * e + 0] = make_float4(centers[3 * e + 0], centers[3 * e + 1], centers[3 * e + 2], lc);
        sp[3 * e + 1] = make_float4(NH * ic00, NH * ic11, NH * ic22, 2.0f * NH * ic01);
        sp[3 * e + 2] = make_float4(2.0f * NH * ic02, 2.0f * NH * ic12, 0.0f, 0.0f);
    }
    __syncthreads();

    long long i = (long long)blockIdx.x * BLOCK + tid;
    float pen = 0.0f;
    if (i < n) {
        const float LOG2E = 1.44269504f;
        float px = pts[3 * i + 0];
        float py = pts[3 * i + 1];
        float pz = pts[3 * i + 2];
        float dl = dists[i] * LOG2E;

        float s = 0.0f;
        float a0 = 0.0f, a1 = 0.0f, a2 = 0.0f, a3 = 0.0f;
#pragma unroll 8
        for (int e = 0; e < EC; ++e) {
            fvec4 a = __builtin_nontemporal_load(&act[(size_t)e * (size_t)n + (size_t)i]);
            float4 c0 = sp[3 * e + 0];
            float4 c1 = sp[3 * e + 1];
            float4 c2 = sp[3 * e + 2];
            float dx = px - c0.x, dy = py - c0.y, dz = pz - c0.z;
            float q = (c1.x * dx + c1.w * dy + c2.x * dz) * dx
                    + (c1.y * dy + c2.y * dz) * dy
                    + (c1.z * dz) * dz + c0.w;
            float v = __builtin_amdgcn_exp2f(q);  // = |c| * exp(-0.5 diff^T invcov diff)
            s += v;
            pen += fabsf(v - 0.005f);
            float s0 = __builtin_amdgcn_rcpf(1.0f + __builtin_amdgcn_exp2f(-LOG2E * a.x));
            float s1 = __builtin_amdgcn_rcpf(1.0f + __builtin_amdgcn_exp2f(-LOG2E * a.y));
            float s2 = __builtin_amdgcn_rcpf(1.0f + __builtin_amdgcn_exp2f(-LOG2E * a.z));
            float al = 1.0f - __builtin_amdgcn_exp2f(-fmaxf(a.w, 0.0f) * dl);
            a0 += v * s0;
            a1 += v * s1;
            a2 += v * s2;
            a3 += v * al;
        }
        float rn = __builtin_amdgcn_rcpf(s + 0.01f);
        fvec4 o;
        o.x = a0 * rn; o.y = a1 * rn; o.z = a2 * rn; o.w = a3 * rn;
        __builtin_nontemporal_store(o, &out[i]);
    }

    // deterministic per-block reduction: wave butterfly then fixed-order LDS combine
    float w = pen;
#pragma unroll
    for (int off = 32; off >= 1; off >>= 1) w += __shfl_xor(w, off);
    if ((tid & 63) == 0) sred[tid >> 6] = w;
    __syncthreads();
    if (tid == 0) {
        float bp = ((sred[0] + sred[1]) + sred[2]) + sred[3];
        unsigned long long contrib =
            (1ULL << CNT_SHIFT) +
            (unsigned long long)((double)bp * PEN_SCALE + 0.5);
        unsigned long long old = atomicAdd(pen_acc, contrib);
        if ((old >> CNT_SHIFT) == (unsigned long long)(nblocks - 1)) {
            unsigned long long total = (old + contrib) & ((1ULL << CNT_SHIFT) - 1);
            *penout = (float)((double)total / PEN_SCALE / (double)n);
        }
    }
}

extern "C" void kernel_launch(void* const* d_in, const int* in_sizes, int n_in,
                              void* d_out, int out_size, void* d_ws, size_t ws_size,
                              hipStream_t stream) {
    const float* pts       = (const float*)d_in[0];  // (N,3)
    const float* act       = (const float*)d_in[1];  // (EC,N,4)
    const float* dists     = (const float*)d_in[2];  // (N,1)
    const float* constants = (const float*)d_in[3];  // (EC,1)
    const float* centers   = (const float*)d_in[4];  // (EC,3)
    const float* radii     = (const float*)d_in[5];  // (EC,1)
    const float* rotations = (const float*)d_in[6];  // (EC,3)
    float* out = (float*)d_out;

    int n = in_sizes[0] / 3;
    unsigned long long* pen_acc = (unsigned long long*)d_ws;

    int nblocks = (n + BLOCK - 1) / BLOCK;

    hipMemsetAsync(d_ws, 0, sizeof(unsigned long long), stream);
    ldif_fused_kernel<<<nblocks, BLOCK, 0, stream>>>(
        pts, (const fvec4*)act, dists, constants, centers, radii, rotations,
        (fvec4*)out, out + (size_t)4 * n, pen_acc, n, nblocks);
}

// Round 7
// 58.766 us; speedup vs baseline: 2.3864x; 1.1217x over previous
//
#include <hip/hip_runtime.h>
#include <math.h>

#define EC 32
#define BLOCK 256
#define REPS 2   // chunks of BLOCK points per block

typedef float fvec4 __attribute__((ext_vector_type(4)));

__global__ __launch_bounds__(BLOCK) void ldif_main_kernel(
    const float* __restrict__ pts,
    const fvec4* __restrict__ act,      // (EC, N) of float4
    const float* __restrict__ dists,
    const float* __restrict__ constants,
    const float* __restrict__ centers,
    const float* __restrict__ radii,
    const float* __restrict__ rotations,
    fvec4* __restrict__ out,
    float* __restrict__ partials,
    int n) {
    // params per component e (3 x float4), computed redundantly per-block:
    //  p0 = (cx, cy, cz, log2|c|)
    //  p1 = (Axx, Ayy, Azz, Axy)   A = -0.5*log2(e)*inv_cov, off-diag doubled
    //  p2 = (Axz, Ayz, 0, 0)
    __shared__ float4 sp[EC * 3];
    __shared__ float sred[4];

    const int tid = threadIdx.x;
    if (tid < EC) {
        int e = tid;
        float r = fabsf(radii[e]);
        float dinv = 1.0f / (r + 1e-8f);
        float rx = rotations[3 * e + 0], ry = rotations[3 * e + 1], rz = rotations[3 * e + 2];
        float cx = cosf(rx), cy = cosf(ry), cz = cosf(rz);
        float sx = sinf(rx), sy = sinf(ry), sz = sinf(rz);
        float R00 = cz * cy, R01 = cz * sy * sx - sz * cx, R02 = cz * sy * cx + sz * sx;
        float R10 = sz * cy, R11 = sz * sy * sx + cz * cx, R12 = sz * sy * cx - cz * sx;
        float R20 = -sy,     R21 = cy * sx,                R22 = cy * cx;
        float ic00 = dinv * (R00 * R00 + R01 * R01 + R02 * R02);
        float ic11 = dinv * (R10 * R10 + R11 * R11 + R12 * R12);
        float ic22 = dinv * (R20 * R20 + R21 * R21 + R22 * R22);
        float ic01 = dinv * (R00 * R10 + R01 * R11 + R02 * R12);
        float ic02 = dinv * (R00 * R20 + R01 * R21 + R02 * R22);
        float ic12 = dinv * (R10 * R20 + R11 * R21 + R12 * R22);
        const float NH = -0.72134752044f;  // -0.5 * log2(e)
        float lc = log2f(fabsf(constants[e]));
        sp[3 * e + 0] = make_float4(centers[3 * e + 0], centers[3 * e + 1], centers[3 * e + 2], lc);
        sp[3 * e + 1] = make_float4(NH * ic00, NH * ic11, NH * ic22, 2.0f * NH * ic01);
        sp[3 * e + 2] = make_float4(2.0f * NH * ic02, 2.0f * NH * ic12, 0.0f, 0.0f);
    }
    __syncthreads();

    float pen = 0.0f;
    const float LOG2E = 1.44269504f;
#pragma unroll 1
    for (int rep = 0; rep < REPS; ++rep) {
        long long i = (long long)blockIdx.x * (BLOCK * REPS) + rep * BLOCK + tid;
        if (i >= n) break;
        float px = pts[3 * i + 0];
        float py = pts[3 * i + 1];
        float pz = pts[3 * i + 2];
        float dl = dists[i] * LOG2E;

        float s = 0.0f;
        float a0 = 0.0f, a1 = 0.0f, a2 = 0.0f, a3 = 0.0f;
#pragma unroll 8
        for (int e = 0; e < EC; ++e) {
            fvec4 a = __builtin_nontemporal_load(&act[(size_t)e * (size_t)n + (size_t)i]);
            float4 c0 = sp[3 * e + 0];
            float4 c1 = sp[3 * e + 1];
            float4 c2 = sp[3 * e + 2];
            float dx = px - c0.x, dy = py - c0.y, dz = pz - c0.z;
            float q = (c1.x * dx + c1.w * dy + c2.x * dz) * dx
                    + (c1.y * dy + c2.y * dz) * dy
                    + (c1.z * dz) * dz + c0.w;
            float v = __builtin_amdgcn_exp2f(q);  // = |c| * exp(-0.5 diff^T invcov diff)
            s += v;
            pen += fabsf(v - 0.005f);
            float s0 = __builtin_amdgcn_rcpf(1.0f + __builtin_amdgcn_exp2f(-LOG2E * a.x));
            float s1 = __builtin_amdgcn_rcpf(1.0f + __builtin_amdgcn_exp2f(-LOG2E * a.y));
            float s2 = __builtin_amdgcn_rcpf(1.0f + __builtin_amdgcn_exp2f(-LOG2E * a.z));
            float al = 1.0f - __builtin_amdgcn_exp2f(-fmaxf(a.w, 0.0f) * dl);
            a0 += v * s0;
            a1 += v * s1;
            a2 += v * s2;
            a3 += v * al;
        }
        float rn = __builtin_amdgcn_rcpf(s + 0.01f);
        fvec4 o;
        o.x = a0 * rn; o.y = a1 * rn; o.z = a2 * rn; o.w = a3 * rn;
        __builtin_nontemporal_store(o, &out[i]);
    }

    // deterministic per-block reduction: wave butterfly then fixed-order LDS combine
    float w = pen;
#pragma unroll
    for (int off = 32; off >= 1; off >>= 1) w += __shfl_xor(w, off);
    if ((tid & 63) == 0) sred[tid >> 6] = w;
    __syncthreads();
    if (tid == 0) partials[blockIdx.x] = ((sred[0] + sred[1]) + sred[2]) + sred[3];
}

__global__ __launch_bounds__(BLOCK) void ldif_reduce_kernel(
    const float* __restrict__ partials, int nparts, float* __restrict__ out, int n) {
    __shared__ double rd[BLOCK];
    int tid = threadIdx.x;
    double s = 0.0;
    for (int j = tid; j < nparts; j += BLOCK) s += (double)partials[j];
    rd[tid] = s;
    __syncthreads();
    for (int st = BLOCK / 2; st > 0; st >>= 1) {
        if (tid < st) rd[tid] += rd[tid + st];
        __syncthreads();
    }
    if (tid == 0) out[0] = (float)(rd[0] / (double)n);
}

extern "C" void kernel_launch(void* const* d_in, const int* in_sizes, int n_in,
                              void* d_out, int out_size, void* d_ws, size_t ws_size,
                              hipStream_t stream) {
    const float* pts       = (const float*)d_in[0];  // (N,3)
    const float* act       = (const float*)d_in[1];  // (EC,N,4)
    const float* dists     = (const float*)d_in[2];  // (N,1)
    const float* constants = (const float*)d_in[3];  // (EC,1)
    const float* centers   = (const float*)d_in[4];  // (EC,3)
    const float* radii     = (const float*)d_in[5];  // (EC,1)
    const float* rotations = (const float*)d_in[6];  // (EC,3)
    float* out = (float*)d_out;

    int n = in_sizes[0] / 3;
    float* partials = (float*)d_ws;

    int nblocks = (n + BLOCK * REPS - 1) / (BLOCK * REPS);

    ldif_main_kernel<<<nblocks, BLOCK, 0, stream>>>(
        pts, (const fvec4*)act, dists, constants, centers, radii, rotations,
        (fvec4*)out, partials, n);
    ldif_reduce_kernel<<<1, BLOCK, 0, stream>>>(partials, nblocks, out + (size_t)4 * n, n);
}

// Round 8
// 53.278 us; speedup vs baseline: 2.6323x; 1.1030x over previous
//
#include <hip/hip_runtime.h>
#include <math.h>

#define EC 32
#define BLOCK 256

typedef float fvec4 __attribute__((ext_vector_type(4)));

// Hierarchical fenceless penalty reduction:
//   level 1: 64 line-padded u64 accumulators; block b -> line b%64.
//   level 2: one final u64.
// Each u64 packs: bits [0,52) fixed-point sum (scale 2^22), bits [52,64) count.
// Integer atomic adds commute exactly -> bit-deterministic, order-independent;
// the finisher of each level is detected from the returned count bits. No fences.
#define PEN_SCALE 4194304.0   // 2^22
#define CNT_SHIFT 52
#define MASK52 ((1ULL << 52) - 1)
#define NLINES 64
#define LINE_STRIDE 8         // u64s per line (64 bytes)

__global__ __launch_bounds__(BLOCK) void ldif_fused_kernel(
    const float* __restrict__ pts,
    const fvec4* __restrict__ act,      // (EC, N) of float4
    const float* __restrict__ dists,
    const float* __restrict__ constants,
    const float* __restrict__ centers,
    const float* __restrict__ radii,
    const float* __restrict__ rotations,
    fvec4* __restrict__ out,
    float* __restrict__ penout,         // &out_flat[4*n]
    unsigned long long* __restrict__ lines,   // NLINES * LINE_STRIDE u64, zeroed
    unsigned long long* __restrict__ final_acc, // 1 u64, zeroed
    int n, int nblocks) {
    // params per component e (3 x float4), computed redundantly per-block:
    //  p0 = (cx, cy, cz, log2|c|)
    //  p1 = (Axx, Ayy, Azz, Axy)   A = -0.5*log2(e)*inv_cov, off-diag doubled
    //  p2 = (Axz, Ayz, 0, 0)
    __shared__ float4 sp[EC * 3];
    __shared__ float sred[4];

    const int tid = threadIdx.x;
    if (tid < EC) {
        int e = tid;
        float r = fabsf(radii[e]);
        float dinv = 1.0f / (r + 1e-8f);
        float rx = rotations[3 * e + 0], ry = rotations[3 * e + 1], rz = rotations[3 * e + 2];
        float cx = cosf(rx), cy = cosf(ry), cz = cosf(rz);
        float sx = sinf(rx), sy = sinf(ry), sz = sinf(rz);
        float R00 = cz * cy, R01 = cz * sy * sx - sz * cx, R02 = cz * sy * cx + sz * sx;
        float R10 = sz * cy, R11 = sz * sy * sx + cz * cx, R12 = sz * sy * cx - cz * sx;
        float R20 = -sy,     R21 = cy * sx,                R22 = cy * cx;
        float ic00 = dinv * (R00 * R00 + R01 * R01 + R02 * R02);
        float ic11 = dinv * (R10 * R10 + R11 * R11 + R12 * R12);
        float ic22 = dinv * (R20 * R20 + R21 * R21 + R22 * R22);
        float ic01 = dinv * (R00 * R10 + R01 * R11 + R02 * R12);
        float ic02 = dinv * (R00 * R20 + R01 * R21 + R02 * R22);
        float ic12 = dinv * (R10 * R20 + R11 * R21 + R12 * R22);
        const float NH = -0.72134752044f;  // -0.5 * log2(e)
        float lc = log2f(fabsf(constants[e]));
        sp[3 * e + 0] = make_float4(centers[3 * e + 0], centers[3 * e + 1], centers[3 * e + 2], lc);
        sp[3 * e + 1] = make_float4(NH * ic00, NH * ic11, NH * ic22, 2.0f * NH * ic01);
        sp[3 * e + 2] = make_float4(2.0f * NH * ic02, 2.0f * NH * ic12, 0.0f, 0.0f);
    }
    __syncthreads();

    long long i = (long long)blockIdx.x * BLOCK + tid;
    float pen = 0.0f;
    if (i < n) {
        const float LOG2E = 1.44269504f;
        float px = pts[3 * i + 0];
        float py = pts[3 * i + 1];
        float pz = pts[3 * i + 2];
        float dl = dists[i] * LOG2E;

        float s = 0.0f;
        float a0 = 0.0f, a1 = 0.0f, a2 = 0.0f, a3 = 0.0f;
#pragma unroll 8
        for (int e = 0; e < EC; ++e) {
            fvec4 a = __builtin_nontemporal_load(&act[(size_t)e * (size_t)n + (size_t)i]);
            float4 c0 = sp[3 * e + 0];
            float4 c1 = sp[3 * e + 1];
            float4 c2 = sp[3 * e + 2];
            float dx = px - c0.x, dy = py - c0.y, dz = pz - c0.z;
            float q = (c1.x * dx + c1.w * dy + c2.x * dz) * dx
                    + (c1.y * dy + c2.y * dz) * dy
                    + (c1.z * dz) * dz + c0.w;
            float v = __builtin_amdgcn_exp2f(q);  // = |c| * exp(-0.5 diff^T invcov diff)
            s += v;
            pen += fabsf(v - 0.005f);
            float s0 = __builtin_amdgcn_rcpf(1.0f + __builtin_amdgcn_exp2f(-LOG2E * a.x));
            float s1 = __builtin_amdgcn_rcpf(1.0f + __builtin_amdgcn_exp2f(-LOG2E * a.y));
            float s2 = __builtin_amdgcn_rcpf(1.0f + __builtin_amdgcn_exp2f(-LOG2E * a.z));
            float al = 1.0f - __builtin_amdgcn_exp2f(-fmaxf(a.w, 0.0f) * dl);
            a0 += v * s0;
            a1 += v * s1;
            a2 += v * s2;
            a3 += v * al;
        }
        float rn = __builtin_amdgcn_rcpf(s + 0.01f);
        fvec4 o;
        o.x = a0 * rn; o.y = a1 * rn; o.z = a2 * rn; o.w = a3 * rn;
        __builtin_nontemporal_store(o, &out[i]);
    }

    // deterministic per-block reduction: wave butterfly then fixed-order LDS combine
    float w = pen;
#pragma unroll
    for (int off = 32; off >= 1; off >>= 1) w += __shfl_xor(w, off);
    if ((tid & 63) == 0) sred[tid >> 6] = w;
    __syncthreads();
    if (tid == 0) {
        float bp = ((sred[0] + sred[1]) + sred[2]) + sred[3];
        int line = blockIdx.x & (NLINES - 1);
        unsigned long long contrib =
            (1ULL << CNT_SHIFT) +
            (unsigned long long)((double)bp * PEN_SCALE + 0.5);
        unsigned long long old = atomicAdd(&lines[line * LINE_STRIDE], contrib);
        int expected = (nblocks >> 6) + ((line < (nblocks & (NLINES - 1))) ? 1 : 0);
        if ((old >> CNT_SHIFT) == (unsigned long long)(expected - 1)) {
            // this block completed its line: forward exact line total
            unsigned long long linetotal = (old + contrib) & MASK52;
            unsigned long long c2 = (1ULL << CNT_SHIFT) + linetotal;
            unsigned long long old2 = atomicAdd(final_acc, c2);
            int nlines_active = (nblocks < NLINES) ? nblocks : NLINES;
            if ((old2 >> CNT_SHIFT) == (unsigned long long)(nlines_active - 1)) {
                unsigned long long total = (old2 + c2) & MASK52;
                *penout = (float)((double)total / PEN_SCALE / (double)n);
            }
        }
    }
}

extern "C" void kernel_launch(void* const* d_in, const int* in_sizes, int n_in,
                              void* d_out, int out_size, void* d_ws, size_t ws_size,
                              hipStream_t stream) {
    const float* pts       = (const float*)d_in[0];  // (N,3)
    const float* act       = (const float*)d_in[1];  // (EC,N,4)
    const float* dists     = (const float*)d_in[2];  // (N,1)
    const float* constants = (const float*)d_in[3];  // (EC,1)
    const float* centers   = (const float*)d_in[4];  // (EC,3)
    const float* radii     = (const float*)d_in[5];  // (EC,1)
    const float* rotations = (const float*)d_in[6];  // (EC,3)
    float* out = (float*)d_out;

    int n = in_sizes[0] / 3;
    unsigned long long* lines     = (unsigned long long*)d_ws;                  // 4 KB
    unsigned long long* final_acc = (unsigned long long*)((char*)d_ws + 4096);  // 8 B

    int nblocks = (n + BLOCK - 1) / BLOCK;

    hipMemsetAsync(d_ws, 0, 4096 + 64, stream);
    ldif_fused_kernel<<<nblocks, BLOCK, 0, stream>>>(
        pts, (const fvec4*)act, dists, constants, centers, radii, rotations,
        (fvec4*)out, out + (size_t)4 * n, lines, final_acc, n, nblocks);
}

// Round 9
// 48.616 us; speedup vs baseline: 2.8847x; 1.0959x over previous
//
#include <hip/hip_runtime.h>
#include <math.h>

#define EC 32
#define BLOCK 512   // 8 waves; halves per-block setup vs 256 at same total wave count

typedef float fvec4 __attribute__((ext_vector_type(4)));

__global__ __launch_bounds__(BLOCK) void ldif_main_kernel(
    const float* __restrict__ pts,
    const fvec4* __restrict__ act,      // (EC, N) of float4
    const float* __restrict__ dists,
    const float* __restrict__ constants,
    const float* __restrict__ centers,
    const float* __restrict__ radii,
    const float* __restrict__ rotations,
    fvec4* __restrict__ out,
    float* __restrict__ partials,
    int n) {
    // params per component e (3 x float4), computed redundantly per-block:
    //  p0 = (cx, cy, cz, log2|c|)
    //  p1 = (Axx, Ayy, Azz, Axy)   A = -0.5*log2(e)*inv_cov, off-diag doubled
    //  p2 = (Axz, Ayz, 0, 0)
    __shared__ float4 sp[EC * 3];
    __shared__ float sred[BLOCK / 64];

    const int tid = threadIdx.x;
    if (tid < EC) {
        int e = tid;
        float r = fabsf(radii[e]);
        float dinv = 1.0f / (r + 1e-8f);
        float rx = rotations[3 * e + 0], ry = rotations[3 * e + 1], rz = rotations[3 * e + 2];
        // inputs in [-pi, pi]: fast HW trig is plenty accurate here
        float cx = __cosf(rx), cy = __cosf(ry), cz = __cosf(rz);
        float sx = __sinf(rx), sy = __sinf(ry), sz = __sinf(rz);
        float R00 = cz * cy, R01 = cz * sy * sx - sz * cx, R02 = cz * sy * cx + sz * sx;
        float R10 = sz * cy, R11 = sz * sy * sx + cz * cx, R12 = sz * sy * cx - cz * sx;
        float R20 = -sy,     R21 = cy * sx,                R22 = cy * cx;
        float ic00 = dinv * (R00 * R00 + R01 * R01 + R02 * R02);
        float ic11 = dinv * (R10 * R10 + R11 * R11 + R12 * R12);
        float ic22 = dinv * (R20 * R20 + R21 * R21 + R22 * R22);
        float ic01 = dinv * (R00 * R10 + R01 * R11 + R02 * R12);
        float ic02 = dinv * (R00 * R20 + R01 * R21 + R02 * R22);
        float ic12 = dinv * (R10 * R20 + R11 * R21 + R12 * R22);
        const float NH = -0.72134752044f;  // -0.5 * log2(e)
        float lc = log2f(fabsf(constants[e]));
        sp[3 * e + 0] = make_float4(centers[3 * e + 0], centers[3 * e + 1], centers[3 * e + 2], lc);
        sp[3 * e + 1] = make_float4(NH * ic00, NH * ic11, NH * ic22, 2.0f * NH * ic01);
        sp[3 * e + 2] = make_float4(2.0f * NH * ic02, 2.0f * NH * ic12, 0.0f, 0.0f);
    }
    __syncthreads();

    long long i = (long long)blockIdx.x * BLOCK + tid;
    float pen = 0.0f;
    if (i < n) {
        const float LOG2E = 1.44269504f;
        float px = pts[3 * i + 0];
        float py = pts[3 * i + 1];
        float pz = pts[3 * i + 2];
        float dl = dists[i] * LOG2E;

        float s = 0.0f;
        float a0 = 0.0f, a1 = 0.0f, a2 = 0.0f, a3 = 0.0f;
#pragma unroll 8
        for (int e = 0; e < EC; ++e) {
            fvec4 a = __builtin_nontemporal_load(&act[(size_t)e * (size_t)n + (size_t)i]);
            float4 c0 = sp[3 * e + 0];
            float4 c1 = sp[3 * e + 1];
            float4 c2 = sp[3 * e + 2];
            float dx = px - c0.x, dy = py - c0.y, dz = pz - c0.z;
            float q = (c1.x * dx + c1.w * dy + c2.x * dz) * dx
                    + (c1.y * dy + c2.y * dz) * dy
                    + (c1.z * dz) * dz + c0.w;
            float v = __builtin_amdgcn_exp2f(q);  // = |c| * exp(-0.5 diff^T invcov diff)
            s += v;
            pen += fabsf(v - 0.005f);
            float s0 = __builtin_amdgcn_rcpf(1.0f + __builtin_amdgcn_exp2f(-LOG2E * a.x));
            float s1 = __builtin_amdgcn_rcpf(1.0f + __builtin_amdgcn_exp2f(-LOG2E * a.y));
            float s2 = __builtin_amdgcn_rcpf(1.0f + __builtin_amdgcn_exp2f(-LOG2E * a.z));
            float al = 1.0f - __builtin_amdgcn_exp2f(-fmaxf(a.w, 0.0f) * dl);
            a0 += v * s0;
            a1 += v * s1;
            a2 += v * s2;
            a3 += v * al;
        }
        float rn = __builtin_amdgcn_rcpf(s + 0.01f);
        fvec4 o;
        o.x = a0 * rn; o.y = a1 * rn; o.z = a2 * rn; o.w = a3 * rn;
        __builtin_nontemporal_store(o, &out[i]);
    }

    // deterministic per-block reduction: wave butterfly then fixed-order LDS combine
    float w = pen;
#pragma unroll
    for (int off = 32; off >= 1; off >>= 1) w += __shfl_xor(w, off);
    if ((tid & 63) == 0) sred[tid >> 6] = w;
    __syncthreads();
    if (tid == 0) {
        float bp = ((sred[0] + sred[1]) + (sred[2] + sred[3]))
                 + ((sred[4] + sred[5]) + (sred[6] + sred[7]));
        partials[blockIdx.x] = bp;
    }
}

__global__ __launch_bounds__(256) void ldif_reduce_kernel(
    const float* __restrict__ partials, int nparts, float* __restrict__ out, int n) {
    __shared__ double rd[256];
    int tid = threadIdx.x;
    double s = 0.0;
    for (int j = tid; j < nparts; j += 256) s += (double)partials[j];
    rd[tid] = s;
    __syncthreads();
    for (int st = 128; st > 0; st >>= 1) {
        if (tid < st) rd[tid] += rd[tid + st];
        __syncthreads();
    }
    if (tid == 0) out[0] = (float)(rd[0] / (double)n);
}

extern "C" void kernel_launch(void* const* d_in, const int* in_sizes, int n_in,
                              void* d_out, int out_size, void* d_ws, size_t ws_size,
                              hipStream_t stream) {
    const float* pts       = (const float*)d_in[0];  // (N,3)
    const float* act       = (const float*)d_in[1];  // (EC,N,4)
    const float* dists     = (const float*)d_in[2];  // (N,1)
    const float* constants = (const float*)d_in[3];  // (EC,1)
    const float* centers   = (const float*)d_in[4];  // (EC,3)
    const float* radii     = (const float*)d_in[5];  // (EC,1)
    const float* rotations = (const float*)d_in[6];  // (EC,3)
    float* out = (float*)d_out;

    int n = in_sizes[0] / 3;
    float* partials = (float*)d_ws;

    int nblocks = (n + BLOCK - 1) / BLOCK;

    ldif_main_kernel<<<nblocks, BLOCK, 0, stream>>>(
        pts, (const fvec4*)act, dists, constants, centers, radii, rotations,
        (fvec4*)out, partials, n);
    ldif_reduce_kernel<<<1, 256, 0, stream>>>(partials, nblocks, out + (size_t)4 * n, n);
}